// Round 10
// baseline (969.835 us; speedup 1.0000x reference)
//
#include <hip/hip_runtime.h>
#include <hip/hip_bf16.h>
#include <cstdint>

// Problem constants
#define B_   1024
#define V_   16
#define NH_  32
#define SH_  8
#define D_   128
#define KV_  1024
#define H_   4096

typedef __bf16 bf16;
typedef bf16  bf16x8 __attribute__((ext_vector_type(8)));
typedef float f32x2  __attribute__((ext_vector_type(2)));
typedef float f32x4  __attribute__((ext_vector_type(4)));

#define VMCNT(n) asm volatile("s_waitcnt vmcnt(" #n ")" ::: "memory")
#define LGKM0()  asm volatile("s_waitcnt lgkmcnt(0)" ::: "memory")

// async global->LDS, 16B per lane. LDS dest is wave-uniform base + lane*16.
__device__ __forceinline__ void gl2lds16(const void* g, void* l) {
    __builtin_amdgcn_global_load_lds((const __attribute__((address_space(1))) void*)g,
                                     (__attribute__((address_space(3))) void*)l,
                                     16, 0, 0);
}

// ---------------------------------------------------------------------------
// K1: h1[v][b][k] = tanh(prefix[b][v] * W1[v][k] + b1[v][k])  (bf16 out)
// ---------------------------------------------------------------------------
__global__ __launch_bounds__(256)
void h1_kernel(const float* __restrict__ prefix, const float* __restrict__ W1,
               const float* __restrict__ b1, bf16* __restrict__ h1)
{
    int gid = blockIdx.x * 256 + threadIdx.x;   // V_*B_*KV_/8 = 2M threads
    int k8  = gid & 127;                        // KV_/8 = 128
    int b   = (gid >> 7) & 1023;
    int v   = gid >> 17;
    float x = prefix[b * V_ + v];
    const float* wp = W1 + (size_t)v * KV_ + k8 * 8;
    const float* bp = b1 + (size_t)v * KV_ + k8 * 8;
    f32x4 w0 = *(const f32x4*)wp,       w1 = *(const f32x4*)(wp + 4);
    f32x4 q0 = *(const f32x4*)bp,       q1 = *(const f32x4*)(bp + 4);
    bf16x8 o;
#pragma unroll
    for (int j = 0; j < 4; ++j) o[j]     = (bf16)tanhf(fmaf(x, w0[j], q0[j]));
#pragma unroll
    for (int j = 0; j < 4; ++j) o[4 + j] = (bf16)tanhf(fmaf(x, w1[j], q1[j]));
    *(bf16x8*)(h1 + (size_t)gid * 8) = o;
}

// ---------------------------------------------------------------------------
// K2: pipelined GEMM, fused B-transpose+fp32->bf16.
//   C[v] = A[v] (M=1024 x KDIM, bf16 row-major) * Bf[v] ([KDIM][NDIM] fp32)
// MODE 0: out = tanh(C + bias) -> bf16 [V][M][NDIM]   (h2)
// MODE 1: out = C + bias -> fp32 scattered to [B,NH,V,D], 4-way head rep,
//         via per-wave LDS transpose so every store is 128B contiguous.
//
// 256x256 tile, 512 threads, 8 waves (2m x 4n), 128x64 out/wave, acc[8][4],
// BK=64. LDS 128KB (A dbuf 2x32K, B dbuf 2x32K) -> 1 block/CU, 8 waves.
//
// Block ordering for INTRA-XCD L2 SHARING (the round-10 change): with
// 1 block/CU, each XCD runs rounds of 32 co-resident blocks. Logical order
// is v-major, then M-FASTEST within v: one XCD round = all 4 m-panels x
// 8 n-slabs of ONE v, sweeping K in lockstep. Instantaneous union working
// set (A-window + B-window) ~1-2MB fits the 4MB per-XCD L2, so B is
// fetched from L3 once per ROUND instead of once per m-block:
// request volume 96 -> ~20-24 MB per v.
// Steady step kt: loadBR(kt+1)[16] | stageA(kt+1)[4 gl2lds] | MFMA(kt)
//   | VMCNT(4) retire br | writeB(kt+1) | VMCNT(0) | LGKM0 | s_barrier.
// ---------------------------------------------------------------------------
template<int MODE, int KDIM, int NDIM>
__global__ __launch_bounds__(512)
void gemm_t2(const bf16* __restrict__ A, const float* __restrict__ Bf,
             const float* __restrict__ bias,
             bf16* __restrict__ outB, float* __restrict__ outF)
{
    // aBuf: 2 x 32KB at [0, 65536); bBuf: 2 x 32KB at [65536, 131072)
    __shared__ __align__(16) char smem[131072];

    constexpr int NX  = NDIM / 256;     // n-blocks per v
    constexpr int NMB = 4;              // m-blocks per v
    constexpr int NXY = NX * NMB;       // blocks per v
    const int lin = blockIdx.x + NX * blockIdx.y + NXY * blockIdx.z;
    constexpr int NWG = NXY * 16;
    constexpr int CHK = NWG / 8;        // NWG % 8 == 0 (bijective swizzle)
    const int swz = (lin & 7) * CHK + (lin >> 3);
    const int v   = swz / NXY;
    const int rem = swz - v * NXY;
    const int m0  = (rem & 3) * 256;    // m FASTEST: an XCD round covers all
    const int n0  = (rem >> 2) * 256;   // 4 m-panels x 8 n-slabs of one v

    const int t  = threadIdx.x;
    const int l  = t & 63;
    const int w  = t >> 6;          // wave id 0..7
    const int wr = w >> 2;          // wave row 0..1 (128 rows each)
    const int wc = w & 3;           // wave col 0..3 (64 cols each)
    constexpr int NT = KDIM / 64;
    static_assert(NT >= 4, "NT >= 4");

    const bf16*  Av = A  + (size_t)v * 1024 * KDIM + (size_t)m0 * KDIM;
    const float* Bv = Bf + (size_t)v * KDIM * NDIM + n0;

    f32x4 acc[8][4];
#pragma unroll
    for (int i = 0; i < 8; ++i)
#pragma unroll
        for (int j = 0; j < 4; ++j) acc[i][j] = f32x4{0.f, 0.f, 0.f, 0.f};

    // B staging: thread t covers n = 2*(t&127)+{0,1}, k-rows (t>>7)*16..+15
    const float* bptr = Bv + (size_t)((t >> 7) * 16) * NDIM + 2 * (t & 127);
    f32x2 br[16];

    auto loadBR = [&](int ktile) {
        const float* np = bptr + (size_t)ktile * 64 * NDIM;
#pragma unroll
        for (int j = 0; j < 16; ++j) br[j] = *(const f32x2*)(np + (size_t)j * NDIM);
    };
    auto stageA = [&](int ktile, int ab) {
#pragma unroll
        for (int i = 0; i < 4; ++i) {
            const int off = t + i * 512;            // 0..2047 (16B chunks)
            const int row = off >> 3;               // 0..255
            const int gc  = (off & 7) ^ ((row >> 1) & 7);
            gl2lds16(Av + (size_t)row * KDIM + ktile * 64 + gc * 8,
                     smem + (size_t)ab * 32768 + (size_t)off * 16);
        }
    };
    auto writeB = [&](int bb) {
        bf16* bN = (bf16*)(smem + 65536 + (size_t)bb * 32768);
#pragma unroll
        for (int i = 0; i < 2; ++i)
#pragma unroll
            for (int h = 0; h < 2; ++h) {
                bf16x8 pk;
#pragma unroll
                for (int jj = 0; jj < 8; ++jj) pk[jj] = (bf16)br[h * 8 + jj][i];
                const int n  = 2 * (t & 127) + i;               // 0..255
                const int ch = ((t >> 7) * 2 + h) ^ (t & 7);    // swizzled slot
                *(bf16x8*)(bN + (size_t)n * 64 + ch * 8) = pk;
            }
    };
    auto mfmaStep = [&](int kt) {
        const bf16* aC = (const bf16*)(smem + (size_t)(kt & 1) * 32768);
        const bf16* bC = (const bf16*)(smem + 65536 + (size_t)(kt & 1) * 32768);
#pragma unroll
        for (int kk = 0; kk < 2; ++kk) {
            bf16x8 af[8], bfv[4];
#pragma unroll
            for (int f = 0; f < 8; ++f) {
                const int mr = wr * 128 + f * 16 + (l & 15);
                const int ca = (kk * 4 + (l >> 4)) ^ ((mr >> 1) & 7);
                af[f] = *(const bf16x8*)(aC + (size_t)mr * 64 + ca * 8);
            }
#pragma unroll
            for (int f = 0; f < 4; ++f) {
                const int nr = wc * 64 + f * 16 + (l & 15);
                const int cb = (kk * 4 + (l >> 4)) ^ ((nr >> 1) & 7);
                bfv[f] = *(const bf16x8*)(bC + (size_t)nr * 64 + cb * 8);
            }
#pragma unroll
            for (int fm = 0; fm < 8; ++fm)
#pragma unroll
                for (int fn = 0; fn < 4; ++fn)
                    acc[fm][fn] = __builtin_amdgcn_mfma_f32_16x16x32_bf16(
                        af[fm], bfv[fn], acc[fm][fn], 0, 0, 0);
        }
    };

    // ---- prologue: stage tile 0 ----
    loadBR(0);
    stageA(0, 0);
    VMCNT(4);                       // retire br(0); A(0) still flying
    writeB(0);
    VMCNT(0);                       // A(0) done
    LGKM0();
    __builtin_amdgcn_s_barrier();

    // ---- main loop ----
    for (int kt = 0; kt < NT - 1; ++kt) {
        loadBR(kt + 1);                 // 16 loads, fly under MFMA
        stageA(kt + 1, (kt + 1) & 1);   // 4 gl2lds, fly under MFMA
        mfmaStep(kt);                   // ~64 MFMAs
        VMCNT(4);                       // retire br(kt+1); A(kt+1) may fly
        writeB((kt + 1) & 1);
        VMCNT(0);                       // A(kt+1) done (issued a phase ago)
        LGKM0();
        __builtin_amdgcn_s_barrier();   // publish tiles kt+1
    }
    mfmaStep(NT - 1);                   // last step: compute only

    // ---- epilogue. C/D frag: col = lane&15, row = (lane>>4)*4 + reg ----
    const int rbase = (l >> 4) * 4;
    const int cbase = l & 15;
    if (MODE == 0) {
#pragma unroll
        for (int fn = 0; fn < 4; ++fn) {
            const int nc = n0 + wc * 64 + fn * 16 + cbase;
            const float bv = bias[(size_t)v * NDIM + nc];
#pragma unroll
            for (int fm = 0; fm < 8; ++fm)
#pragma unroll
                for (int j = 0; j < 4; ++j) {
                    const int mr = m0 + wr * 128 + fm * 16 + rbase + j;
                    outB[(size_t)v * 1024 * NDIM + (size_t)mr * NDIM + nc] =
                        (bf16)tanhf(acc[fm][fn][j] + bv);
                }
        }
    } else {
        __syncthreads();   // main-loop LDS reads done before scratch reuse
        // per-wave 128x32 f32 scratch (16KB x 8 waves = 128KB), two 32-col
        // passes; swizzle (c ^ ((r>>2)&1)<<4): write 2-way (free), read full.
        float* scr = (float*)(smem + (size_t)w * 16384);
        const int nb = n0 + wc * 64;     // wave col base (multiple of 64)
        const int sh = nb >> 7;          // slider head
        const int db = nb & 127;         // 0 or 64
#pragma unroll
        for (int p = 0; p < 2; ++p) {
#pragma unroll
            for (int fm = 0; fm < 8; ++fm)
#pragma unroll
                for (int fq = 0; fq < 2; ++fq) {
                    const int fn = 2 * p + fq;
#pragma unroll
                    for (int j = 0; j < 4; ++j) {
                        const int r = fm * 16 + rbase + j;      // 0..127
                        const int c = fq * 16 + cbase;          // 0..31
                        scr[r * 32 + (c ^ (((r >> 2) & 1) << 4))] = acc[fm][fn][j];
                    }
                }
            const int c4   = (l & 7) * 4;
            const int colg = p * 32 + c4;    // col within wave's 64-col strip
            f32x4 bv4;
#pragma unroll
            for (int q = 0; q < 4; ++q)
                bv4[q] = bias[(size_t)v * NDIM + nb + colg + q];
#pragma unroll
            for (int i = 0; i < 16; ++i) {
                const int r = i * 8 + (l >> 3);                 // 0..127
                f32x4 val = *(const f32x4*)&scr[r * 32 + (c4 ^ (((r >> 2) & 1) << 4))];
#pragma unroll
                for (int q = 0; q < 4; ++q) val[q] += bv4[q];
                const int mr = m0 + wr * 128 + r;
                float* pp = outF + (size_t)mr * (NH_ * V_ * D_)
                                 + (size_t)(sh * 4) * (V_ * D_)
                                 + (size_t)v * D_ + db + colg;
                *(f32x4*)(pp)               = val;
                *(f32x4*)(pp + V_ * D_)     = val;
                *(f32x4*)(pp + 2 * V_ * D_) = val;
                *(f32x4*)(pp + 3 * V_ * D_) = val;
            }
        }
    }
}

// ---------------------------------------------------------------------------
__global__ void tail_kernel(const float* __restrict__ af, float* __restrict__ out)
{
    out[0] = af[0];
}

// ---------------------------------------------------------------------------
extern "C" void kernel_launch(void* const* d_in, const int* in_sizes, int n_in,
                              void* d_out, int out_size, void* d_ws, size_t ws_size,
                              hipStream_t stream)
{
    const float* prefix = (const float*)d_in[0];
    const float* W1[2]  = {(const float*)d_in[1], (const float*)d_in[7]};
    const float* b1[2]  = {(const float*)d_in[2], (const float*)d_in[8]};
    const float* W2[2]  = {(const float*)d_in[3], (const float*)d_in[9]};
    const float* b2[2]  = {(const float*)d_in[4], (const float*)d_in[10]};
    const float* W3[2]  = {(const float*)d_in[5], (const float*)d_in[11]};
    const float* b3[2]  = {(const float*)d_in[6], (const float*)d_in[12]};
    const float* afac   = (const float*)d_in[13];

    // workspace: h1 = V*B*KV bf16 (32 MiB), h2 = V*B*H bf16 (128 MiB)
    bf16* h1 = (bf16*)d_ws;
    bf16* h2 = (bf16*)((char*)d_ws + (size_t)33554432);
    float* outp = (float*)d_out;

    for (int m = 0; m < 2; ++m) {
        // h1 = tanh(x*W1 + b1)
        h1_kernel<<<8192, 256, 0, stream>>>(prefix, W1[m], b1[m], h1);
        // h2 = tanh(h1 @ W2 + b2)   (B-transpose fused into staging)
        gemm_t2<0, 1024, 4096><<<dim3(16, 4, 16), 512, 0, stream>>>(
            h1, W2[m], b2[m], h2, nullptr);
        // out = h2 @ W3 + b3, scattered into keys (m=0) / values (m=1)
        gemm_t2<1, 4096, 1024><<<dim3(4, 4, 16), 512, 0, stream>>>(
            h2, W3[m], b3[m], nullptr, outp + (size_t)m * (B_ * NH_ * V_ * D_));
    }
    tail_kernel<<<1, 1, 0, stream>>>(afac, outp + (size_t)2 * B_ * NH_ * V_ * D_);
}

// Round 11
// 913.797 us; speedup vs baseline: 1.0613x; 1.0613x over previous
//
#include <hip/hip_runtime.h>
#include <hip/hip_bf16.h>
#include <cstdint>

// Problem constants
#define B_   1024
#define V_   16
#define NH_  32
#define SH_  8
#define D_   128
#define KV_  1024
#define H_   4096

typedef __bf16 bf16;
typedef bf16  bf16x8 __attribute__((ext_vector_type(8)));
typedef float f32x2  __attribute__((ext_vector_type(2)));
typedef float f32x4  __attribute__((ext_vector_type(4)));

#define VMCNT(n) asm volatile("s_waitcnt vmcnt(" #n ")" ::: "memory")
#define LGKM0()  asm volatile("s_waitcnt lgkmcnt(0)" ::: "memory")

// async global->LDS, 16B per lane. LDS dest is wave-uniform base + lane*16.
__device__ __forceinline__ void gl2lds16(const void* g, void* l) {
    __builtin_amdgcn_global_load_lds((const __attribute__((address_space(1))) void*)g,
                                     (__attribute__((address_space(3))) void*)l,
                                     16, 0, 0);
}

// ---------------------------------------------------------------------------
// K1: h1[m][v][b][k] = tanh(prefix[b][v] * W1m[v][k] + b1m[v][k])  (bf16)
// Both encoders (m=0 key, m=1 value) in one launch.
// ---------------------------------------------------------------------------
__global__ __launch_bounds__(256)
void h1_kernel(const float* __restrict__ prefix,
               const float* __restrict__ W1a, const float* __restrict__ b1a,
               const float* __restrict__ W1b, const float* __restrict__ b1b,
               bf16* __restrict__ h1)
{
    int gid = blockIdx.x * 256 + threadIdx.x;   // 2*V*B*KV/8 = 4M threads
    int k8  = gid & 127;                        // KV_/8 = 128
    int b   = (gid >> 7) & 1023;
    int vm  = gid >> 17;                        // 0..31
    int v   = vm & 15;
    const float* W1 = (vm >> 4) ? W1b : W1a;
    const float* b1 = (vm >> 4) ? b1b : b1a;
    float x = prefix[b * V_ + v];
    const float* wp = W1 + (size_t)v * KV_ + k8 * 8;
    const float* bp = b1 + (size_t)v * KV_ + k8 * 8;
    f32x4 w0 = *(const f32x4*)wp,       w1 = *(const f32x4*)(wp + 4);
    f32x4 q0 = *(const f32x4*)bp,       q1 = *(const f32x4*)(bp + 4);
    bf16x8 o;
#pragma unroll
    for (int j = 0; j < 4; ++j) o[j]     = (bf16)tanhf(fmaf(x, w0[j], q0[j]));
#pragma unroll
    for (int j = 0; j < 4; ++j) o[4 + j] = (bf16)tanhf(fmaf(x, w1[j], q1[j]));
    *(bf16x8*)(h1 + (size_t)gid * 8) = o;
}

// ---------------------------------------------------------------------------
// K2: pipelined GEMM, fused B-transpose+fp32->bf16, both m in one launch.
//   C[m][v] = A_m[v] (1024 x KDIM bf16) * Bf_m[v] ([KDIM][NDIM] fp32)
// MODE 0: out = tanh(C + bias) -> bf16 h2[m][v][1024][NDIM]
// MODE 1: out = C + bias -> fp32 scattered to [B,NH,V,D] (+m offset), 4-way
//         head rep, LDS-transposed 128B-contiguous NON-TEMPORAL stores
//         (out is never re-read; keep W3/h2 in L2/L3 instead).
//
// 256x256 tile, 512 threads, 8 waves (2m x 4n), 128x64 out/wave, acc[8][4],
// BK=64. LDS 128KB (A dbuf 2x32K, B dbuf 2x32K) -> 1 block/CU, 8 waves.
// Decode (R9-proven): XCD-chunked swizzle, then m-index slowest, v, then
// m0 slower than n0 within v. Merging both m halves the launch tails
// (GEMM2 was a single 256-block round per call).
// Steady step kt: loadBR(kt+1)[16] | stageA(kt+1)[4 gl2lds] | MFMA(kt)
//   | VMCNT(4) retire br | writeB(kt+1) | VMCNT(0) | LGKM0 | s_barrier.
// ---------------------------------------------------------------------------
template<int MODE, int KDIM, int NDIM>
__global__ __launch_bounds__(512)
void gemm_t2(const bf16* __restrict__ A0, const bf16* __restrict__ A1,
             const float* __restrict__ Bf0, const float* __restrict__ Bf1,
             const float* __restrict__ bias0, const float* __restrict__ bias1,
             bf16* __restrict__ outB0, bf16* __restrict__ outB1,
             float* __restrict__ outF)
{
    // aBuf: 2 x 32KB at [0, 65536); bBuf: 2 x 32KB at [65536, 131072)
    __shared__ __align__(16) char smem[131072];

    constexpr int NX  = NDIM / 256;     // n-blocks per v
    constexpr int NMB = 4;              // m-blocks per v
    constexpr int NXY = NX * NMB;       // blocks per v
    const int lin = blockIdx.x + NX * blockIdx.y + NXY * blockIdx.z;
    constexpr int NWG = NXY * 32;       // both m
    constexpr int CHK = NWG / 8;        // NWG % 8 == 0 (bijective swizzle)
    const int swz = (lin & 7) * CHK + (lin >> 3);
    const int mm  = swz / (NXY * 16);           // encoder index 0/1
    const int r2  = swz - mm * (NXY * 16);
    const int v   = r2 / NXY;
    const int rem = r2 - v * NXY;
    const int m0  = (rem / NX) * 256;           // m slower than n (R9)
    const int n0  = (rem - (rem / NX) * NX) * 256;

    const bf16*  Abase = mm ? A1 : A0;
    const float* Bbase = mm ? Bf1 : Bf0;
    const float* bias  = mm ? bias1 : bias0;

    const int t  = threadIdx.x;
    const int l  = t & 63;
    const int w  = t >> 6;          // wave id 0..7
    const int wr = w >> 2;          // wave row 0..1 (128 rows each)
    const int wc = w & 3;           // wave col 0..3 (64 cols each)
    constexpr int NT = KDIM / 64;
    static_assert(NT >= 4, "NT >= 4");

    const bf16*  Av = Abase + (size_t)v * 1024 * KDIM + (size_t)m0 * KDIM;
    const float* Bv = Bbase + (size_t)v * KDIM * NDIM + n0;

    f32x4 acc[8][4];
#pragma unroll
    for (int i = 0; i < 8; ++i)
#pragma unroll
        for (int j = 0; j < 4; ++j) acc[i][j] = f32x4{0.f, 0.f, 0.f, 0.f};

    // B staging: thread t covers n = 2*(t&127)+{0,1}, k-rows (t>>7)*16..+15
    const float* bptr = Bv + (size_t)((t >> 7) * 16) * NDIM + 2 * (t & 127);
    f32x2 br[16];

    auto loadBR = [&](int ktile) {
        const float* np = bptr + (size_t)ktile * 64 * NDIM;
#pragma unroll
        for (int j = 0; j < 16; ++j) br[j] = *(const f32x2*)(np + (size_t)j * NDIM);
    };
    auto stageA = [&](int ktile, int ab) {
#pragma unroll
        for (int i = 0; i < 4; ++i) {
            const int off = t + i * 512;            // 0..2047 (16B chunks)
            const int row = off >> 3;               // 0..255
            const int gc  = (off & 7) ^ ((row >> 1) & 7);
            gl2lds16(Av + (size_t)row * KDIM + ktile * 64 + gc * 8,
                     smem + (size_t)ab * 32768 + (size_t)off * 16);
        }
    };
    auto writeB = [&](int bb) {
        bf16* bN = (bf16*)(smem + 65536 + (size_t)bb * 32768);
#pragma unroll
        for (int i = 0; i < 2; ++i)
#pragma unroll
            for (int h = 0; h < 2; ++h) {
                bf16x8 pk;
#pragma unroll
                for (int jj = 0; jj < 8; ++jj) pk[jj] = (bf16)br[h * 8 + jj][i];
                const int n  = 2 * (t & 127) + i;               // 0..255
                const int ch = ((t >> 7) * 2 + h) ^ (t & 7);    // swizzled slot
                *(bf16x8*)(bN + (size_t)n * 64 + ch * 8) = pk;
            }
    };
    auto mfmaStep = [&](int kt) {
        const bf16* aC = (const bf16*)(smem + (size_t)(kt & 1) * 32768);
        const bf16* bC = (const bf16*)(smem + 65536 + (size_t)(kt & 1) * 32768);
#pragma unroll
        for (int kk = 0; kk < 2; ++kk) {
            bf16x8 af[8], bfv[4];
#pragma unroll
            for (int f = 0; f < 8; ++f) {
                const int mr = wr * 128 + f * 16 + (l & 15);
                const int ca = (kk * 4 + (l >> 4)) ^ ((mr >> 1) & 7);
                af[f] = *(const bf16x8*)(aC + (size_t)mr * 64 + ca * 8);
            }
#pragma unroll
            for (int f = 0; f < 4; ++f) {
                const int nr = wc * 64 + f * 16 + (l & 15);
                const int cb = (kk * 4 + (l >> 4)) ^ ((nr >> 1) & 7);
                bfv[f] = *(const bf16x8*)(bC + (size_t)nr * 64 + cb * 8);
            }
#pragma unroll
            for (int fm = 0; fm < 8; ++fm)
#pragma unroll
                for (int fn = 0; fn < 4; ++fn)
                    acc[fm][fn] = __builtin_amdgcn_mfma_f32_16x16x32_bf16(
                        af[fm], bfv[fn], acc[fm][fn], 0, 0, 0);
        }
    };

    // ---- prologue: stage tile 0 ----
    loadBR(0);
    stageA(0, 0);
    VMCNT(4);                       // retire br(0); A(0) still flying
    writeB(0);
    VMCNT(0);                       // A(0) done
    LGKM0();
    __builtin_amdgcn_s_barrier();

    // ---- main loop ----
    for (int kt = 0; kt < NT - 1; ++kt) {
        loadBR(kt + 1);                 // 16 loads, fly under MFMA
        stageA(kt + 1, (kt + 1) & 1);   // 4 gl2lds, fly under MFMA
        mfmaStep(kt);                   // ~64 MFMAs
        VMCNT(4);                       // retire br(kt+1); A(kt+1) may fly
        writeB((kt + 1) & 1);
        VMCNT(0);                       // A(kt+1) done (issued a phase ago)
        LGKM0();
        __builtin_amdgcn_s_barrier();   // publish tiles kt+1
    }
    mfmaStep(NT - 1);                   // last step: compute only

    // ---- epilogue. C/D frag: col = lane&15, row = (lane>>4)*4 + reg ----
    const int rbase = (l >> 4) * 4;
    const int cbase = l & 15;
    if (MODE == 0) {
        bf16* outB = mm ? outB1 : outB0;
#pragma unroll
        for (int fn = 0; fn < 4; ++fn) {
            const int nc = n0 + wc * 64 + fn * 16 + cbase;
            const float bv = bias[(size_t)v * NDIM + nc];
#pragma unroll
            for (int fm = 0; fm < 8; ++fm)
#pragma unroll
                for (int j = 0; j < 4; ++j) {
                    const int mr = m0 + wr * 128 + fm * 16 + rbase + j;
                    outB[(size_t)v * 1024 * NDIM + (size_t)mr * NDIM + nc] =
                        (bf16)tanhf(acc[fm][fn][j] + bv);
                }
        }
    } else {
        float* outm = outF + (size_t)mm * ((size_t)B_ * NH_ * V_ * D_);
        __syncthreads();   // main-loop LDS reads done before scratch reuse
        // per-wave 128x32 f32 scratch (16KB x 8 waves = 128KB), two 32-col
        // passes; swizzle (c ^ ((r>>2)&1)<<4): write 2-way (free), read full.
        float* scr = (float*)(smem + (size_t)w * 16384);
        const int nb = n0 + wc * 64;     // wave col base (multiple of 64)
        const int sh = nb >> 7;          // slider head
        const int db = nb & 127;         // 0 or 64
#pragma unroll
        for (int p = 0; p < 2; ++p) {
#pragma unroll
            for (int fm = 0; fm < 8; ++fm)
#pragma unroll
                for (int fq = 0; fq < 2; ++fq) {
                    const int fn = 2 * p + fq;
#pragma unroll
                    for (int j = 0; j < 4; ++j) {
                        const int r = fm * 16 + rbase + j;      // 0..127
                        const int c = fq * 16 + cbase;          // 0..31
                        scr[r * 32 + (c ^ (((r >> 2) & 1) << 4))] = acc[fm][fn][j];
                    }
                }
            const int c4   = (l & 7) * 4;
            const int colg = p * 32 + c4;    // col within wave's 64-col strip
            f32x4 bv4;
#pragma unroll
            for (int q = 0; q < 4; ++q)
                bv4[q] = bias[(size_t)v * NDIM + nb + colg + q];
#pragma unroll
            for (int i = 0; i < 16; ++i) {
                const int r = i * 8 + (l >> 3);                 // 0..127
                f32x4 val = *(const f32x4*)&scr[r * 32 + (c4 ^ (((r >> 2) & 1) << 4))];
#pragma unroll
                for (int q = 0; q < 4; ++q) val[q] += bv4[q];
                const int mr = m0 + wr * 128 + r;
                float* pp = outm + (size_t)mr * (NH_ * V_ * D_)
                                 + (size_t)(sh * 4) * (V_ * D_)
                                 + (size_t)v * D_ + db + colg;
                // out is write-only: non-temporal, don't evict W3/h2
                __builtin_nontemporal_store(val, (f32x4*)(pp));
                __builtin_nontemporal_store(val, (f32x4*)(pp + V_ * D_));
                __builtin_nontemporal_store(val, (f32x4*)(pp + 2 * V_ * D_));
                __builtin_nontemporal_store(val, (f32x4*)(pp + 3 * V_ * D_));
            }
        }
    }
}

// ---------------------------------------------------------------------------
__global__ void tail_kernel(const float* __restrict__ af, float* __restrict__ out)
{
    out[0] = af[0];
}

// ---------------------------------------------------------------------------
extern "C" void kernel_launch(void* const* d_in, const int* in_sizes, int n_in,
                              void* d_out, int out_size, void* d_ws, size_t ws_size,
                              hipStream_t stream)
{
    const float* prefix = (const float*)d_in[0];
    const float* W1[2]  = {(const float*)d_in[1], (const float*)d_in[7]};
    const float* b1[2]  = {(const float*)d_in[2], (const float*)d_in[8]};
    const float* W2[2]  = {(const float*)d_in[3], (const float*)d_in[9]};
    const float* b2[2]  = {(const float*)d_in[4], (const float*)d_in[10]};
    const float* W3[2]  = {(const float*)d_in[5], (const float*)d_in[11]};
    const float* b3[2]  = {(const float*)d_in[6], (const float*)d_in[12]};
    const float* afac   = (const float*)d_in[13];

    // workspace: h1[2] = 2x32MiB, h2[2] = 2x128MiB  (ws is ~2.1 GB)
    bf16* h1  = (bf16*)d_ws;                                   // [m][v][b][k]
    bf16* h2a = (bf16*)((char*)d_ws + (size_t)67108864);
    bf16* h2b = (bf16*)((char*)d_ws + (size_t)67108864 + (size_t)134217728);
    float* outp = (float*)d_out;

    // h1 for both encoders
    h1_kernel<<<16384, 256, 0, stream>>>(prefix, W1[0], b1[0], W1[1], b1[1], h1);
    // h2 = tanh(h1 @ W2 + b2), both m in one 2048-block launch
    gemm_t2<0, 1024, 4096><<<dim3(16, 4, 32), 512, 0, stream>>>(
        h1, h1 + (size_t)16777216, W2[0], W2[1], b2[0], b2[1],
        h2a, h2b, nullptr);
    // out = h2 @ W3 + b3, keys+values in one 512-block launch
    gemm_t2<1, 4096, 1024><<<dim3(4, 4, 32), 512, 0, stream>>>(
        h2a, h2b, W3[0], W3[1], b3[0], b3[1],
        nullptr, nullptr, outp);
    tail_kernel<<<1, 1, 0, stream>>>(afac, outp + (size_t)2 * B_ * NH_ * V_ * D_);
}

// Round 12
// 867.707 us; speedup vs baseline: 1.1177x; 1.0531x over previous
//
#include <hip/hip_runtime.h>
#include <hip/hip_bf16.h>
#include <cstdint>

// Problem constants
#define B_   1024
#define V_   16
#define NH_  32
#define SH_  8
#define D_   128
#define KV_  1024
#define H_   4096

typedef __bf16 bf16;
typedef bf16  bf16x8 __attribute__((ext_vector_type(8)));
typedef float f32x2  __attribute__((ext_vector_type(2)));
typedef float f32x4  __attribute__((ext_vector_type(4)));

#define VMCNT(n) asm volatile("s_waitcnt vmcnt(" #n ")" ::: "memory")
#define LGKM0()  asm volatile("s_waitcnt lgkmcnt(0)" ::: "memory")

// async global->LDS, 16B per lane. LDS dest is wave-uniform base + lane*16.
__device__ __forceinline__ void gl2lds16(const void* g, void* l) {
    __builtin_amdgcn_global_load_lds((const __attribute__((address_space(1))) void*)g,
                                     (__attribute__((address_space(3))) void*)l,
                                     16, 0, 0);
}

// ---------------------------------------------------------------------------
// K1: h1[m][v][b][k] = tanh(prefix[b][v] * W1m[v][k] + b1m[v][k])  (bf16)
// Both encoders (m=0 key, m=1 value) in one launch.
// ---------------------------------------------------------------------------
__global__ __launch_bounds__(256)
void h1_kernel(const float* __restrict__ prefix,
               const float* __restrict__ W1a, const float* __restrict__ b1a,
               const float* __restrict__ W1b, const float* __restrict__ b1b,
               bf16* __restrict__ h1)
{
    int gid = blockIdx.x * 256 + threadIdx.x;   // 2*V*B*KV/8 = 4M threads
    int k8  = gid & 127;                        // KV_/8 = 128
    int b   = (gid >> 7) & 1023;
    int vm  = gid >> 17;                        // 0..31
    int v   = vm & 15;
    const float* W1 = (vm >> 4) ? W1b : W1a;
    const float* b1 = (vm >> 4) ? b1b : b1a;
    float x = prefix[b * V_ + v];
    const float* wp = W1 + (size_t)v * KV_ + k8 * 8;
    const float* bp = b1 + (size_t)v * KV_ + k8 * 8;
    f32x4 w0 = *(const f32x4*)wp,       w1 = *(const f32x4*)(wp + 4);
    f32x4 q0 = *(const f32x4*)bp,       q1 = *(const f32x4*)(bp + 4);
    bf16x8 o;
#pragma unroll
    for (int j = 0; j < 4; ++j) o[j]     = (bf16)tanhf(fmaf(x, w0[j], q0[j]));
#pragma unroll
    for (int j = 0; j < 4; ++j) o[4 + j] = (bf16)tanhf(fmaf(x, w1[j], q1[j]));
    *(bf16x8*)(h1 + (size_t)gid * 8) = o;
}

// ---------------------------------------------------------------------------
// K2: pipelined GEMM, fused B-transpose+fp32->bf16, both m in one launch.
//   C[m][v] = A_m[v] (1024 x KDIM bf16) * Bf_m[v] ([KDIM][NDIM] fp32)
// MODE 0: out = tanh(C + bias) -> bf16 h2[m][v][1024][NDIM], via per-wave
//         LDS transpose -> full-128B-line non-temporal stores (round-12 fix:
//         the old scalar-scatter stores caused 2.4x write RMW amplification,
//         WRITE_SIZE 640 MB vs 268 ideal).
// MODE 1: out = C + bias -> fp32 scattered to [B,NH,V,D] (+m offset), 4-way
//         head rep, LDS-transposed 128B-contiguous non-temporal stores.
//
// 256x256 tile, 512 threads, 8 waves (2m x 4n), 128x64 out/wave, acc[8][4],
// BK=64. LDS 128KB (A dbuf 2x32K, B dbuf 2x32K) -> 1 block/CU, 8 waves.
// Decode (R9-proven): XCD-chunked swizzle, m-index slowest, then v, then
// m0 slower than n0 within v.
// Steady step kt: loadBR(kt+1)[16] | stageA(kt+1)[4 gl2lds] | MFMA(kt)
//   | VMCNT(4) retire br | writeB(kt+1) | VMCNT(0) | LGKM0 | s_barrier.
// ---------------------------------------------------------------------------
template<int MODE, int KDIM, int NDIM>
__global__ __launch_bounds__(512)
void gemm_t2(const bf16* __restrict__ A0, const bf16* __restrict__ A1,
             const float* __restrict__ Bf0, const float* __restrict__ Bf1,
             const float* __restrict__ bias0, const float* __restrict__ bias1,
             bf16* __restrict__ outB0, bf16* __restrict__ outB1,
             float* __restrict__ outF)
{
    // aBuf: 2 x 32KB at [0, 65536); bBuf: 2 x 32KB at [65536, 131072)
    __shared__ __align__(16) char smem[131072];

    constexpr int NX  = NDIM / 256;     // n-blocks per v
    constexpr int NMB = 4;              // m-blocks per v
    constexpr int NXY = NX * NMB;       // blocks per v
    const int lin = blockIdx.x + NX * blockIdx.y + NXY * blockIdx.z;
    constexpr int NWG = NXY * 32;       // both m
    constexpr int CHK = NWG / 8;        // NWG % 8 == 0 (bijective swizzle)
    const int swz = (lin & 7) * CHK + (lin >> 3);
    const int mm  = swz / (NXY * 16);           // encoder index 0/1
    const int r2  = swz - mm * (NXY * 16);
    const int v   = r2 / NXY;
    const int rem = r2 - v * NXY;
    const int m0  = (rem / NX) * 256;           // m slower than n (R9)
    const int n0  = (rem - (rem / NX) * NX) * 256;

    const bf16*  Abase = mm ? A1 : A0;
    const float* Bbase = mm ? Bf1 : Bf0;
    const float* bias  = mm ? bias1 : bias0;

    const int t  = threadIdx.x;
    const int l  = t & 63;
    const int w  = t >> 6;          // wave id 0..7
    const int wr = w >> 2;          // wave row 0..1 (128 rows each)
    const int wc = w & 3;           // wave col 0..3 (64 cols each)
    constexpr int NT = KDIM / 64;
    static_assert(NT >= 4, "NT >= 4");

    const bf16*  Av = Abase + (size_t)v * 1024 * KDIM + (size_t)m0 * KDIM;
    const float* Bv = Bbase + (size_t)v * KDIM * NDIM + n0;

    f32x4 acc[8][4];
#pragma unroll
    for (int i = 0; i < 8; ++i)
#pragma unroll
        for (int j = 0; j < 4; ++j) acc[i][j] = f32x4{0.f, 0.f, 0.f, 0.f};

    // B staging: thread t covers n = 2*(t&127)+{0,1}, k-rows (t>>7)*16..+15
    const float* bptr = Bv + (size_t)((t >> 7) * 16) * NDIM + 2 * (t & 127);
    f32x2 br[16];

    auto loadBR = [&](int ktile) {
        const float* np = bptr + (size_t)ktile * 64 * NDIM;
#pragma unroll
        for (int j = 0; j < 16; ++j) br[j] = *(const f32x2*)(np + (size_t)j * NDIM);
    };
    auto stageA = [&](int ktile, int ab) {
#pragma unroll
        for (int i = 0; i < 4; ++i) {
            const int off = t + i * 512;            // 0..2047 (16B chunks)
            const int row = off >> 3;               // 0..255
            const int gc  = (off & 7) ^ ((row >> 1) & 7);
            gl2lds16(Av + (size_t)row * KDIM + ktile * 64 + gc * 8,
                     smem + (size_t)ab * 32768 + (size_t)off * 16);
        }
    };
    auto writeB = [&](int bb) {
        bf16* bN = (bf16*)(smem + 65536 + (size_t)bb * 32768);
#pragma unroll
        for (int i = 0; i < 2; ++i)
#pragma unroll
            for (int h = 0; h < 2; ++h) {
                bf16x8 pk;
#pragma unroll
                for (int jj = 0; jj < 8; ++jj) pk[jj] = (bf16)br[h * 8 + jj][i];
                const int n  = 2 * (t & 127) + i;               // 0..255
                const int ch = ((t >> 7) * 2 + h) ^ (t & 7);    // swizzled slot
                *(bf16x8*)(bN + (size_t)n * 64 + ch * 8) = pk;
            }
    };
    auto mfmaStep = [&](int kt) {
        const bf16* aC = (const bf16*)(smem + (size_t)(kt & 1) * 32768);
        const bf16* bC = (const bf16*)(smem + 65536 + (size_t)(kt & 1) * 32768);
#pragma unroll
        for (int kk = 0; kk < 2; ++kk) {
            bf16x8 af[8], bfv[4];
#pragma unroll
            for (int f = 0; f < 8; ++f) {
                const int mr = wr * 128 + f * 16 + (l & 15);
                const int ca = (kk * 4 + (l >> 4)) ^ ((mr >> 1) & 7);
                af[f] = *(const bf16x8*)(aC + (size_t)mr * 64 + ca * 8);
            }
#pragma unroll
            for (int f = 0; f < 4; ++f) {
                const int nr = wc * 64 + f * 16 + (l & 15);
                const int cb = (kk * 4 + (l >> 4)) ^ ((nr >> 1) & 7);
                bfv[f] = *(const bf16x8*)(bC + (size_t)nr * 64 + cb * 8);
            }
#pragma unroll
            for (int fm = 0; fm < 8; ++fm)
#pragma unroll
                for (int fn = 0; fn < 4; ++fn)
                    acc[fm][fn] = __builtin_amdgcn_mfma_f32_16x16x32_bf16(
                        af[fm], bfv[fn], acc[fm][fn], 0, 0, 0);
        }
    };

    // ---- prologue: stage tile 0 ----
    loadBR(0);
    stageA(0, 0);
    VMCNT(4);                       // retire br(0); A(0) still flying
    writeB(0);
    VMCNT(0);                       // A(0) done
    LGKM0();
    __builtin_amdgcn_s_barrier();

    // ---- main loop ----
    for (int kt = 0; kt < NT - 1; ++kt) {
        loadBR(kt + 1);                 // 16 loads, fly under MFMA
        stageA(kt + 1, (kt + 1) & 1);   // 4 gl2lds, fly under MFMA
        mfmaStep(kt);                   // ~64 MFMAs
        VMCNT(4);                       // retire br(kt+1); A(kt+1) may fly
        writeB((kt + 1) & 1);
        VMCNT(0);                       // A(kt+1) done (issued a phase ago)
        LGKM0();
        __builtin_amdgcn_s_barrier();   // publish tiles kt+1
    }
    mfmaStep(NT - 1);                   // last step: compute only

    // ---- epilogue. C/D frag: col = lane&15, row = (lane>>4)*4 + reg ----
    const int rbase = (l >> 4) * 4;
    const int cbase = l & 15;
    if (MODE == 0) {
        bf16* outB = mm ? outB1 : outB0;
        __syncthreads();   // main-loop LDS reads done before scratch reuse
        // per-wave 128x64 bf16 scratch (16KB x 8 = 128KB). Write swizzled
        // (c ^ ((r>>2)&3)<<4): each quarter-wave hits a disjoint bank octet
        // (conflict-free). Read back 8 consecutive cols/lane -> 8 lanes
        // cover a full 128B row -> full-line non-temporal stores (kills the
        // 2.4x write RMW amplification of the old scalar-scatter stores).
        bf16* scr = (bf16*)(smem + (size_t)w * 16384);   // [128][64]
#pragma unroll
        for (int fn = 0; fn < 4; ++fn) {
            const int c  = fn * 16 + cbase;              // 0..63
            const float bv = bias[(size_t)v * NDIM + n0 + wc * 64 + c];
#pragma unroll
            for (int fm = 0; fm < 8; ++fm)
#pragma unroll
                for (int j = 0; j < 4; ++j) {
                    const int r = fm * 16 + rbase + j;   // 0..127
                    scr[r * 64 + (c ^ (((r >> 2) & 3) << 4))] =
                        (bf16)tanhf(acc[fm][fn][j] + bv);
                }
        }
        const int c8 = (l & 7) * 8;                      // lane's 8-col group
#pragma unroll
        for (int i = 0; i < 16; ++i) {
            const int r  = i * 8 + (l >> 3);             // 0..127
            bf16x8 val = *(const bf16x8*)&scr[r * 64 + (c8 ^ (((r >> 2) & 3) << 4))];
            const int mr = m0 + wr * 128 + r;
            const int nc = n0 + wc * 64 + c8;
            __builtin_nontemporal_store(val,
                (bf16x8*)(outB + (size_t)v * 1024 * NDIM + (size_t)mr * NDIM + nc));
        }
    } else {
        float* outm = outF + (size_t)mm * ((size_t)B_ * NH_ * V_ * D_);
        __syncthreads();   // main-loop LDS reads done before scratch reuse
        // per-wave 128x32 f32 scratch (16KB x 8 waves = 128KB), two 32-col
        // passes; swizzle (c ^ ((r>>2)&1)<<4): write 2-way (free), read full.
        float* scr = (float*)(smem + (size_t)w * 16384);
        const int nb = n0 + wc * 64;     // wave col base (multiple of 64)
        const int sh = nb >> 7;          // slider head
        const int db = nb & 127;         // 0 or 64
#pragma unroll
        for (int p = 0; p < 2; ++p) {
#pragma unroll
            for (int fm = 0; fm < 8; ++fm)
#pragma unroll
                for (int fq = 0; fq < 2; ++fq) {
                    const int fn = 2 * p + fq;
#pragma unroll
                    for (int j = 0; j < 4; ++j) {
                        const int r = fm * 16 + rbase + j;      // 0..127
                        const int c = fq * 16 + cbase;          // 0..31
                        scr[r * 32 + (c ^ (((r >> 2) & 1) << 4))] = acc[fm][fn][j];
                    }
                }
            const int c4   = (l & 7) * 4;
            const int colg = p * 32 + c4;    // col within wave's 64-col strip
            f32x4 bv4;
#pragma unroll
            for (int q = 0; q < 4; ++q)
                bv4[q] = bias[(size_t)v * NDIM + nb + colg + q];
#pragma unroll
            for (int i = 0; i < 16; ++i) {
                const int r = i * 8 + (l >> 3);                 // 0..127
                f32x4 val = *(const f32x4*)&scr[r * 32 + (c4 ^ (((r >> 2) & 1) << 4))];
#pragma unroll
                for (int q = 0; q < 4; ++q) val[q] += bv4[q];
                const int mr = m0 + wr * 128 + r;
                float* pp = outm + (size_t)mr * (NH_ * V_ * D_)
                                 + (size_t)(sh * 4) * (V_ * D_)
                                 + (size_t)v * D_ + db + colg;
                // out is write-only: non-temporal, don't evict W3/h2
                __builtin_nontemporal_store(val, (f32x4*)(pp));
                __builtin_nontemporal_store(val, (f32x4*)(pp + V_ * D_));
                __builtin_nontemporal_store(val, (f32x4*)(pp + 2 * V_ * D_));
                __builtin_nontemporal_store(val, (f32x4*)(pp + 3 * V_ * D_));
            }
        }
    }
}

// ---------------------------------------------------------------------------
__global__ void tail_kernel(const float* __restrict__ af, float* __restrict__ out)
{
    out[0] = af[0];
}

// ---------------------------------------------------------------------------
extern "C" void kernel_launch(void* const* d_in, const int* in_sizes, int n_in,
                              void* d_out, int out_size, void* d_ws, size_t ws_size,
                              hipStream_t stream)
{
    const float* prefix = (const float*)d_in[0];
    const float* W1[2]  = {(const float*)d_in[1], (const float*)d_in[7]};
    const float* b1[2]  = {(const float*)d_in[2], (const float*)d_in[8]};
    const float* W2[2]  = {(const float*)d_in[3], (const float*)d_in[9]};
    const float* b2[2]  = {(const float*)d_in[4], (const float*)d_in[10]};
    const float* W3[2]  = {(const float*)d_in[5], (const float*)d_in[11]};
    const float* b3[2]  = {(const float*)d_in[6], (const float*)d_in[12]};
    const float* afac   = (const float*)d_in[13];

    // workspace: h1[2] = 2x32MiB, h2[2] = 2x128MiB  (ws is ~2.1 GB)
    bf16* h1  = (bf16*)d_ws;                                   // [m][v][b][k]
    bf16* h2a = (bf16*)((char*)d_ws + (size_t)67108864);
    bf16* h2b = (bf16*)((char*)d_ws + (size_t)67108864 + (size_t)134217728);
    float* outp = (float*)d_out;

    // h1 for both encoders
    h1_kernel<<<16384, 256, 0, stream>>>(prefix, W1[0], b1[0], W1[1], b1[1], h1);
    // h2 = tanh(h1 @ W2 + b2), both m in one 2048-block launch
    gemm_t2<0, 1024, 4096><<<dim3(16, 4, 32), 512, 0, stream>>>(
        h1, h1 + (size_t)16777216, W2[0], W2[1], b2[0], b2[1],
        h2a, h2b, nullptr);
    // out = h2 @ W3 + b3, keys+values in one 512-block launch
    gemm_t2<1, 4096, 1024><<<dim3(4, 4, 32), 512, 0, stream>>>(
        h2a, h2b, W3[0], W3[1], b3[0], b3[1],
        nullptr, nullptr, outp);
    tail_kernel<<<1, 1, 0, stream>>>(afac, outp + (size_t)2 * B_ * NH_ * V_ * D_);
}